// Round 17
// baseline (71.523 us; speedup 1.0000x reference)
//
#include <hip/hip_runtime.h>
#include <hip/hip_bf16.h>

#define BB 4096
#define NNB 20
#define GG 4
#define DIN 128
#define EE 64
#define HH 8

typedef short bf16x8 __attribute__((ext_vector_type(8)));
typedef float f32x4 __attribute__((ext_vector_type(4)));

__device__ __forceinline__ float lrelu_f(float x) { return x > 0.f ? x : 0.2f * x; }
__device__ __forceinline__ unsigned short f2bf(float f) {
  unsigned u = __float_as_uint(f);
  return (unsigned short)((u + 0x7fffu + ((u >> 16) & 1u)) >> 16);
}
__device__ __forceinline__ float bf2f(unsigned short s) {
  return __uint_as_float(((unsigned)s) << 16);
}
// packed f32x2 -> bf16x2 (RNE); maps to v_cvt_pk_bf16_f32 on gfx950
__device__ __forceinline__ unsigned pkbf(float a, float b) {
  __hip_bfloat162 p = __float22bfloat162_rn(make_float2(a, b));
  return *(unsigned*)&p;
}

// ---------------- K0: prep (unchanged, cold) ----------------
__global__ __launch_bounds__(256) void prep_kernel(
    const float* __restrict__ W_heads, const float* __restrict__ a_self,
    const float* __restrict__ a_neigh, const float* __restrict__ W_out,
    unsigned short* __restrict__ P1Whi, unsigned short* __restrict__ P1Wlo,
    unsigned short* __restrict__ WBhi, unsigned short* __restrict__ WBlo,
    unsigned short* __restrict__ WOhi, unsigned short* __restrict__ WOlo) {
  int id = blockIdx.x * 256 + threadIdx.x;
  if (id < 2048) {
    int j = id & 7, lane = (id >> 3) & 63, kb = id >> 9;
    int col = lane & 15, k = kb * 32 + (lane >> 4) * 8 + j;
    int h = col & 7;
    const float* a = (col < 8) ? a_neigh : a_self;
    const float* Wrow = W_heads + (h * DIN + k) * EE;
    float acc = 0.f;
    for (int e = 0; e < EE; ++e) acc = fmaf(Wrow[e], a[h * EE + e], acc);
    unsigned short hi = f2bf(acc);
    P1Whi[id] = hi;
    P1Wlo[id] = f2bf(acc - bf2f(hi));
  } else if (id < 2048 + 65536) {
    int rel = id - 2048;   // (((h*4+nt)*4+kb)*64 + l)*8 + j
    int j = rel & 7, l = (rel >> 3) & 63, kb = (rel >> 9) & 3, nt = (rel >> 11) & 3, h = rel >> 13;
    int d = kb * 32 + (l >> 4) * 8 + j;
    int e = nt * 16 + (l & 15);
    float w = W_heads[(h * DIN + d) * EE + e];
    unsigned short hi = f2bf(w);
    WBhi[rel] = hi;
    WBlo[rel] = f2bf(w - bf2f(hi));
  } else if (id < 2048 + 65536 + 32768) {
    int rel = id - 2048 - 65536;  // ((nt*16+kb)*64 + l)*8 + j
    int j = rel & 7, l = (rel >> 3) & 63, kb = (rel >> 9) & 15, nt = rel >> 13;
    int k = kb * 32 + (l >> 4) * 8 + j;
    int n = nt * 16 + (l & 15);
    float w = W_out[k * EE + n];
    unsigned short hi = f2bf(w);
    WOhi[rel] = hi;
    WOlo[rel] = f2bf(w - bf2f(hi));
  }
}

// ---------------- Fused kernel: 512 threads (8 waves), 4 b's = 16 bg rows ----------------
// LDS 57,344 B (2 blocks/CU):
//   [0,32768):     P1: wf staging [0,8192). P3+: agg bf16 [bg16][h8][d128],
//                  byte ^ ((bg&7)<<4).
//   [32768,49152): P1-P3: att f32, word = n*128 + bg*8 + h. B-C: h bf16
//                  [row16][k512], byte ^ ((row&7)<<4).
//   [49152,57344): pad (occupancy control)
// R17: all hot-path f32->bf16 conversions use packed cvt (pkbf) -> v_cvt_pk_bf16_f32.
__global__ __launch_bounds__(512, 4) void fused_kernel(
    const float* __restrict__ self_vecs, const float* __restrict__ neigh_vecs,
    const unsigned short* __restrict__ P1Whi, const unsigned short* __restrict__ P1Wlo,
    const unsigned short* __restrict__ WBhi, const unsigned short* __restrict__ WBlo,
    const unsigned short* __restrict__ WOhi, const unsigned short* __restrict__ WOlo,
    float* __restrict__ out) {
  __shared__ char smem[57344];
  char* aggb = smem;
  float* attw = (float*)(smem + 32768);
  char* hb = smem + 32768;

  const int t = threadIdx.x;
  const int w = t >> 6, lane = t & 63;
  const int m = lane & 15, kg = lane >> 4;
  const int bid = blockIdx.x;

#define LOAD_X(X, ptr)                                                         \
  {                                                                            \
    const float4* p_ = (const float4*)(ptr);                                   \
    _Pragma("unroll") for (int q = 0; q < 4; ++q) {                            \
      X[2 * q]     = p_[q * 8 + kg * 2];                                       \
      X[2 * q + 1] = p_[q * 8 + kg * 2 + 1];                                   \
    }                                                                          \
  }

  // ---- packed convert + 8 MFMA for one tile; wf read from LDS [0,8192) ----
#define PROC_TILE(X, cvec)                                                     \
  {                                                                            \
    _Pragma("unroll") for (int kb = 0; kb < 4; ++kb) {                         \
      int4 xi;                                                                 \
      xi.x = (int)pkbf(X[2 * kb].x, X[2 * kb].y);                              \
      xi.y = (int)pkbf(X[2 * kb].z, X[2 * kb].w);                              \
      xi.z = (int)pkbf(X[2 * kb + 1].x, X[2 * kb + 1].y);                      \
      xi.w = (int)pkbf(X[2 * kb + 1].z, X[2 * kb + 1].w);                      \
      bf16x8 xh = *(bf16x8*)&xi;                                               \
      bf16x8 wh = *(const bf16x8*)(smem + kb * 1024 + lane * 16);              \
      bf16x8 wl = *(const bf16x8*)(smem + 4096 + kb * 1024 + lane * 16);       \
      cvec = __builtin_amdgcn_mfma_f32_16x16x32_bf16(xh, wh, cvec, 0, 0, 0);   \
      cvec = __builtin_amdgcn_mfma_f32_16x16x32_bf16(xh, wl, cvec, 0, 0, 0);   \
    }                                                                          \
  }

#define P1_SOFTMAX(tile, cvec)                                                 \
  if (m < 8) {                                                                 \
    float l[4], mx = -1e30f;                                                   \
    _Pragma("unroll") for (int gg = 0; gg < 4; ++gg) {                         \
      float v = lrelu_f(fs[gg] + (cvec)[gg]);                                  \
      l[gg] = v;                                                               \
      mx = fmaxf(mx, v);                                                       \
    }                                                                          \
    float s = 0.f;                                                             \
    _Pragma("unroll") for (int gg = 0; gg < 4; ++gg) {                         \
      l[gg] = __expf(l[gg] - mx);                                              \
      s += l[gg];                                                              \
    }                                                                          \
    float inv = 1.f / s;                                                       \
    _Pragma("unroll") for (int gg = 0; gg < 4; ++gg)                           \
      attw[(tile) * 128 + (kg * 4 + gg) * 8 + m] = l[gg] * inv;                \
  }

  const int bl_m = m >> 2, g_m = m & 3;
  const float* base_n =
      neigh_vecs + ((size_t)(bid * 4 + bl_m) * NNB * GG + g_m) * DIN;

  // ---- issue self + tile-A loads (in flight across the staging barrier) ----
  float4 XS[8], XA[8], XB[8], XC[8];
  LOAD_X(XS, self_vecs + ((size_t)bid * 16 + m) * DIN)
  LOAD_X(XA, base_n + (size_t)w * (GG * DIN))

  // ---- stage P1 weights into LDS [0,8192) ----
  {
    const float4* src = (t < 256) ? (const float4*)P1Whi : (const float4*)P1Wlo;
    ((float4*)smem)[t] = src[t & 255];
  }
  __syncthreads();

  // ======== P1a: self tile (redundant per wave) ========
  f32x4 fs;
  {
    f32x4 c20 = {0.f, 0.f, 0.f, 0.f};
    PROC_TILE(XS, c20)
#pragma unroll
    for (int reg = 0; reg < 4; ++reg) fs[reg] = __shfl_xor(c20[reg], 8);
  }
  LOAD_X(XB, base_n + (size_t)(w + 8) * (GG * DIN))

  // ======== P1b: n-tiles ========
  f32x4 cA = {0.f, 0.f, 0.f, 0.f}, cB = {0.f, 0.f, 0.f, 0.f};
  PROC_TILE(XA, cA)
  if (w < 4) LOAD_X(XC, base_n + (size_t)(w + 16) * (GG * DIN))
  PROC_TILE(XB, cB)
  if (w < 4) {
    f32x4 cC = {0.f, 0.f, 0.f, 0.f};
    PROC_TILE(XC, cC)
    P1_SOFTMAX(w + 16, cC)
  }
  P1_SOFTMAX(w, cA)
  P1_SOFTMAX(w + 8, cB)
  __syncthreads();   // att complete; wf staging dead -> agg region free

  // ======== P3: dual-bg. Lane covers bg = 2w + (lane>=32), d = 4*(lane&31)..+4 ========
  {
    const int ih = lane >> 5;
    const int bg = 2 * w + ih;
    const int bl = w >> 1;
    const int g0 = (2 * w) & 3;
    const float* nb2 =
        neigh_vecs + ((size_t)(bid * 4 + bl) * NNB * GG + g0) * DIN;
    const int dl = 4 * (lane & 31);
    float acc[8][4];
#pragma unroll
    for (int h = 0; h < 8; ++h)
#pragma unroll
      for (int d = 0; d < 4; ++d) acc[h][d] = 0.f;
#pragma unroll
    for (int n = 0; n < NNB; ++n) {
      float4 x4 = *(const float4*)&nb2[(size_t)n * GG * DIN + 4 * lane];
      f32x4 a0 = *(const f32x4*)&attw[n * 128 + bg * 8];
      f32x4 a1 = *(const f32x4*)&attw[n * 128 + bg * 8 + 4];
#pragma unroll
      for (int h = 0; h < 4; ++h) {
        acc[h][0] = fmaf(a0[h], x4.x, acc[h][0]);
        acc[h][1] = fmaf(a0[h], x4.y, acc[h][1]);
        acc[h][2] = fmaf(a0[h], x4.z, acc[h][2]);
        acc[h][3] = fmaf(a0[h], x4.w, acc[h][3]);
        acc[h + 4][0] = fmaf(a1[h], x4.x, acc[h + 4][0]);
        acc[h + 4][1] = fmaf(a1[h], x4.y, acc[h + 4][1]);
        acc[h + 4][2] = fmaf(a1[h], x4.z, acc[h + 4][2]);
        acc[h + 4][3] = fmaf(a1[h], x4.w, acc[h + 4][3]);
      }
    }
    const int swz = (bg & 7) << 4;
#pragma unroll
    for (int h = 0; h < 8; ++h) {
      uint2 pk;
      pk.x = pkbf(acc[h][0], acc[h][1]);
      pk.y = pkbf(acc[h][2], acc[h][3]);
      *(uint2*)(aggb + ((bg * 2048 + h * 256 + 2 * dl) ^ swz)) = pk;
    }
  }
  __syncthreads();   // agg complete; att dead -> hb reuse

  // ======== phase B: head transform, wave w -> hh = w; h stored bf16 ========
  {
    const int hh = w;
    const int aswz = (m & 7) << 4;
    bf16x8 a[4];
#pragma unroll
    for (int kb = 0; kb < 4; ++kb)
      a[kb] = *(const bf16x8*)(aggb + ((m * 2048 + hh * 256 + kb * 64 + kg * 16) ^ aswz));
#pragma unroll
    for (int nt = 0; nt < 4; ++nt) {
      f32x4 c = {0.f, 0.f, 0.f, 0.f};
#pragma unroll
      for (int kb = 0; kb < 4; ++kb) {
        const int fi = (((hh * 4 + nt) * 4 + kb) * 64 + lane) * 8;
        bf16x8 bh = *(const bf16x8*)(WBhi + fi);
        bf16x8 bl_ = *(const bf16x8*)(WBlo + fi);
        c = __builtin_amdgcn_mfma_f32_16x16x32_bf16(a[kb], bh, c, 0, 0, 0);
        c = __builtin_amdgcn_mfma_f32_16x16x32_bf16(a[kb], bl_, c, 0, 0, 0);
      }
      const int k = hh * 64 + nt * 16 + m;
      // packed convert, rows differ per reg -> u16 stores of lo/hi halves
      unsigned u01 = pkbf(lrelu_f(c[0]), lrelu_f(c[1]));
      unsigned u23 = pkbf(lrelu_f(c[2]), lrelu_f(c[3]));
#pragma unroll
      for (int reg = 0; reg < 4; ++reg) {
        int row = kg * 4 + reg;
        int byte = (row * 1024 + k * 2) ^ ((row & 7) << 4);
        unsigned v = (reg < 2) ? u01 : u23;
        unsigned short s16 = (reg & 1) ? (unsigned short)(v >> 16)
                                       : (unsigned short)(v & 0xffffu);
        *(unsigned short*)(hb + byte) = s16;
      }
    }
  }
  __syncthreads();

  // ======== phase C: final FC, waves 0..3, nt = w ========
  if (w < 4) {
    const int nt = w;
    f32x4 acc = {0.f, 0.f, 0.f, 0.f};
    for (int kb = 0; kb < 16; ++kb) {
      int byte = (m * 1024 + (kb * 32 + kg * 8) * 2) ^ ((m & 7) << 4);
      bf16x8 ah = *(const bf16x8*)(hb + byte);
      const int fi = ((nt * 16 + kb) * 64 + lane) * 8;
      bf16x8 bh = *(const bf16x8*)(WOhi + fi);
      bf16x8 bl_ = *(const bf16x8*)(WOlo + fi);
      acc = __builtin_amdgcn_mfma_f32_16x16x32_bf16(ah, bh, acc, 0, 0, 0);
      acc = __builtin_amdgcn_mfma_f32_16x16x32_bf16(ah, bl_, acc, 0, 0, 0);
    }
    const int rbase = bid * 16;
#pragma unroll
    for (int reg = 0; reg < 4; ++reg) {
      int row = rbase + kg * 4 + reg;
      out[(size_t)row * EE + nt * 16 + m] = fmaxf(acc[reg], 0.f);
    }
  }
#undef LOAD_X
#undef PROC_TILE
#undef P1_SOFTMAX
}

extern "C" void kernel_launch(void* const* d_in, const int* in_sizes, int n_in,
                              void* d_out, int out_size, void* d_ws, size_t ws_size,
                              hipStream_t stream) {
  (void)in_sizes; (void)n_in; (void)out_size; (void)ws_size;
  const float* self_vecs  = (const float*)d_in[0];
  const float* neigh_vecs = (const float*)d_in[1];
  const float* W_heads    = (const float*)d_in[2];
  const float* a_self     = (const float*)d_in[3];
  const float* a_neigh    = (const float*)d_in[4];
  const float* W_out      = (const float*)d_in[5];
  float* out              = (float*)d_out;

  char* ws = (char*)d_ws;
  unsigned short* P1Whi = (unsigned short*)ws;                    // 4 KB
  unsigned short* P1Wlo = (unsigned short*)(ws + 4096);           // 4 KB
  unsigned short* WBhi  = (unsigned short*)(ws + 8192);           // 128 KB
  unsigned short* WBlo  = (unsigned short*)(ws + 8192 + 131072);
  unsigned short* WOhi  = (unsigned short*)(ws + 8192 + 262144);  // 64 KB
  unsigned short* WOlo  = (unsigned short*)(ws + 8192 + 262144 + 65536);

  prep_kernel<<<(2048 + 65536 + 32768) / 256, 256, 0, stream>>>(
      W_heads, a_self, a_neigh, W_out, P1Whi, P1Wlo, WBhi, WBlo, WOhi, WOlo);

  fused_kernel<<<BB / 4, 512, 0, stream>>>(
      self_vecs, neigh_vecs, P1Whi, P1Wlo, WBhi, WBlo, WOhi, WOlo, out);
}